// Round 1
// baseline (461.203 us; speedup 1.0000x reference)
//
#include <hip/hip_runtime.h>
#include <hip/hip_bf16.h>

typedef __attribute__((ext_vector_type(8))) short short8;
typedef __attribute__((ext_vector_type(4))) float f32x4;

#define HW 65536
#define NPOS 32768

// ---------------------------------------------------------------------------
// K1: fused conv(phi,g,theta) + exp + global-sum partials + att outer-product.
// Grid (64, 8): blockIdx.x = column-chunk (8 tiles of 64 cols), blockIdx.y = b.
// Block 256 = 4 waves; wave og owns 24 of the 96 conv outputs, lane = column.
// ---------------------------------------------------------------------------
__global__ __launch_bounds__(256) void k1_conv(
    const float* __restrict__ x, const float* __restrict__ wphi,
    const float* __restrict__ wtheta, const float* __restrict__ wg,
    __hip_bfloat16* __restrict__ Tg, float* __restrict__ attG,
    float* __restrict__ sums)
{
  __shared__ float xs[64][64];        // one half's x tile: 64c x 64n
  __shared__ float Ep[64][65];        // exp(phi) in view layout [c'=2i+h][n]
  __shared__ float Eg[64][65];        // exp(g)
  __shared__ float rbuf[8];

  const int tid = threadIdx.x;
  const int b = blockIdx.y, cb = blockIdx.x;
  const int lane = tid & 63;
  const int og = __builtin_amdgcn_readfirstlane(tid >> 6);  // wave id (uniform)
  const float* xb = x + (size_t)b * 64 * HW;
  __hip_bfloat16* Tb = Tg + (size_t)b * 64 * NPOS;

  float attacc[4][4] = {};
  float sp = 0.f, sg = 0.f;
  const int ccb = tid >> 4, cdb = tid & 15;  // att tiling: c-block, d-block

  for (int t = 0; t < 8; ++t) {
    const int n0 = (cb * 8 + t) * 64;
    for (int h = 0; h < 2; ++h) {
      __syncthreads();  // protect xs/Ep/Eg from previous phase readers
      // stage x tile for this half (coalesced float4)
      for (int k = tid; k < 64 * 16; k += 256) {
        const int c = k >> 4, q = k & 15;
        const float4 v = *(const float4*)(xb + (size_t)c * HW + h * NPOS + n0 + q * 4);
        *(float4*)&xs[c][q * 4] = v;
      }
      __syncthreads();
      // x column -> 64 VGPRs, then pure FMA with scalar-loaded weights
      float xr[64];
      #pragma unroll
      for (int c = 0; c < 64; ++c) xr[c] = xs[c][lane];
      #pragma unroll 4
      for (int j = 0; j < 24; ++j) {
        const int u = og * 24 + j;  // wave-uniform output index
        const float* wrow = (u < 32) ? (wphi + u * 64)
                          : (u < 64) ? (wg + (u - 32) * 64)
                                     : (wtheta + (u - 64) * 64);
        float acc = 0.f;
        #pragma unroll
        for (int c = 0; c < 64; ++c) acc = __builtin_fmaf(wrow[c], xr[c], acc);
        if (u < 32) {
          const float e = __expf(acc);
          Ep[2 * u + h][lane] = e; sp += e;
        } else if (u < 64) {
          const float e = __expf(acc);
          Eg[2 * (u - 32) + h][lane] = e; sg += e;
        } else {
          // theta, natural view layout: row d = 2i+h, col n0+lane (coalesced bf16)
          Tb[(size_t)(2 * (u - 64) + h) * NPOS + n0 + lane] = __float2bfloat16(acc);
        }
      }
    }
    __syncthreads();
    // att partial: att[c][d] += sum_n Eg[c][n]*Ep[d][n]  (64x64x64 per tile)
    for (int n = 0; n < 64; ++n) {
      float gv[4], pv[4];
      #pragma unroll
      for (int i = 0; i < 4; ++i) { gv[i] = Eg[ccb * 4 + i][n]; pv[i] = Ep[cdb * 4 + i][n]; }
      #pragma unroll
      for (int i = 0; i < 4; ++i)
        #pragma unroll
        for (int j = 0; j < 4; ++j)
          attacc[i][j] = __builtin_fmaf(gv[i], pv[j], attacc[i][j]);
    }
  }
  // flush att partials (zeroed by memset before launch)
  float* attB = attG + b * 4096;
  #pragma unroll
  for (int i = 0; i < 4; ++i)
    #pragma unroll
    for (int j = 0; j < 4; ++j)
      atomicAdd(&attB[(ccb * 4 + i) * 64 + cdb * 4 + j], attacc[i][j]);
  // softmax denominators
  #pragma unroll
  for (int off = 32; off > 0; off >>= 1) {
    sp += __shfl_down(sp, off);
    sg += __shfl_down(sg, off);
  }
  if (lane == 0) { rbuf[og] = sp; rbuf[4 + og] = sg; }
  __syncthreads();
  if (tid == 0) {
    atomicAdd(&sums[b],     rbuf[0] + rbuf[1] + rbuf[2] + rbuf[3]);
    atomicAdd(&sums[8 + b], rbuf[4] + rbuf[5] + rbuf[6] + rbuf[7]);
  }
}

// ---------------------------------------------------------------------------
// K3: M[b][h][o][d] = (1/(Sp*Sg)) * sum_i wm[o][i] * att[b][2i+h][d]  (bf16)
// ---------------------------------------------------------------------------
__global__ __launch_bounds__(256) void k3_mmat(
    const float* __restrict__ attG, const float* __restrict__ sums,
    const float* __restrict__ wm, __hip_bfloat16* __restrict__ M)
{
  __shared__ float att_s[64][64];
  __shared__ float wms[64][32];
  const int tid = threadIdx.x;
  const int b = blockIdx.x >> 1, h = blockIdx.x & 1;
  const float* attB = attG + b * 4096;
  for (int k = tid; k < 4096; k += 256) att_s[k >> 6][k & 63] = attB[k];
  for (int k = tid; k < 2048; k += 256) wms[k >> 5][k & 31] = wm[k];
  __syncthreads();
  const float scale = 1.f / (sums[b] * sums[8 + b]);
  for (int idx = tid; idx < 4096; idx += 256) {
    const int o = idx >> 6, d = idx & 63;
    float a = 0.f;
    #pragma unroll
    for (int i = 0; i < 32; ++i)
      a = __builtin_fmaf(wms[o][i], att_s[2 * i + h][d], a);
    M[(size_t)((b * 2 + h) * 64 + o) * 64 + d] = __float2bfloat16(a * scale);
  }
}

// ---------------------------------------------------------------------------
// K4: out[b][o][h*32768+n] = sum_d M[b][h][o][d] * Tv[d][n]   (MFMA bf16)
// Grid (64, 8). Block 256 = 4 waves, wave owns o-range [16w,16w+16).
// ---------------------------------------------------------------------------
__global__ __launch_bounds__(256) void k4_out(
    const __hip_bfloat16* __restrict__ Tg, const __hip_bfloat16* __restrict__ M,
    float* __restrict__ out)
{
  __shared__ unsigned short Mlds[2][64][88];  // [h][o][d] padded rows (16B-aligned)
  __shared__ unsigned short Tlds[64][88];     // transposed: [n][d]
  const int tid = threadIdx.x;
  const int b = blockIdx.y, cb = blockIdx.x;
  const unsigned short* Tb = (const unsigned short*)Tg + (size_t)b * 64 * NPOS;
  const unsigned short* Mb = (const unsigned short*)M + (size_t)b * 2 * 4096;

  for (int k = tid; k < 2048; k += 256) {
    const int h = k >> 10, o = (k >> 4) & 63, q = k & 15;
    const ushort4 v = *(const ushort4*)(Mb + (size_t)(h * 64 + o) * 64 + q * 4);
    *(ushort4*)&Mlds[h][o][q * 4] = v;
  }
  const int wave = tid >> 6, lane = tid & 63;
  const int lr = lane & 15;            // A row / B col / D col
  const int lkb = (lane >> 4) * 8;     // k-offset of this lane's 8 elements
  float* outb = out + (size_t)b * 64 * HW;

  for (int t = 0; t < 8; ++t) {
    const int n0 = (cb * 8 + t) * 64;
    __syncthreads();
    // stage T tile transposed: global [d][n] (coalesced ushort4) -> LDS [n][d]
    for (int k = tid; k < 1024; k += 256) {
      const int d = k >> 4, q = k & 15;
      const ushort4 v = *(const ushort4*)(Tb + (size_t)d * NPOS + n0 + q * 4);
      Tlds[q * 4 + 0][d] = v.x; Tlds[q * 4 + 1][d] = v.y;
      Tlds[q * 4 + 2][d] = v.z; Tlds[q * 4 + 3][d] = v.w;
    }
    __syncthreads();
    #pragma unroll
    for (int h = 0; h < 2; ++h) {
      #pragma unroll
      for (int nb = 0; nb < 4; ++nb) {
        f32x4 acc = {0.f, 0.f, 0.f, 0.f};
        #pragma unroll
        for (int ks = 0; ks < 2; ++ks) {
          const short8 av = *(const short8*)&Mlds[h][wave * 16 + lr][ks * 32 + lkb];
          const short8 bv = *(const short8*)&Tlds[nb * 16 + lr][ks * 32 + lkb];
          acc = __builtin_amdgcn_mfma_f32_16x16x32_bf16(av, bv, acc, 0, 0, 0);
        }
        // D: col = lane&15, row = (lane>>4)*4 + reg
        float* o0 = outb + (size_t)(wave * 16 + (lane >> 4) * 4) * HW
                  + (size_t)h * NPOS + n0 + nb * 16 + lr;
        #pragma unroll
        for (int r = 0; r < 4; ++r) o0[(size_t)r * HW] = acc[r];
      }
    }
  }
}

// ---------------------------------------------------------------------------
extern "C" void kernel_launch(void* const* d_in, const int* in_sizes, int n_in,
                              void* d_out, int out_size, void* d_ws, size_t ws_size,
                              hipStream_t stream)
{
  const float* x      = (const float*)d_in[0];
  const float* wphi   = (const float*)d_in[1];
  const float* wtheta = (const float*)d_in[2];
  const float* wg     = (const float*)d_in[3];
  const float* wm     = (const float*)d_in[4];
  float* out = (float*)d_out;

  char* ws = (char*)d_ws;
  __hip_bfloat16* Tg = (__hip_bfloat16*)ws;                       // 33,554,432 B
  __hip_bfloat16* M  = (__hip_bfloat16*)(ws + 33554432);          //    131,072 B
  float* attG        = (float*)(ws + 33554432 + 131072);          //    131,072 B
  float* sums        = (float*)(ws + 33554432 + 262144);          //         64 B

  hipMemsetAsync(attG, 0, 131072 + 64, stream);
  k1_conv<<<dim3(64, 8), 256, 0, stream>>>(x, wphi, wtheta, wg, Tg, attG, sums);
  k3_mmat<<<dim3(16), 256, 0, stream>>>(attG, sums, wm, M);
  k4_out<<<dim3(64, 8), 256, 0, stream>>>(Tg, M, out);
}

// Round 2
// 306.855 us; speedup vs baseline: 1.5030x; 1.5030x over previous
//
#include <hip/hip_runtime.h>

typedef __attribute__((ext_vector_type(8))) short short8;
typedef __attribute__((ext_vector_type(4))) float f32x4;

#define HW 65536
#define NPOS 32768

__device__ __forceinline__ unsigned short f2bf(float f) {
  unsigned u = __builtin_bit_cast(unsigned, f);
  u += 0x7fffu + ((u >> 16) & 1u);
  return (unsigned short)(u >> 16);
}
__device__ __forceinline__ float bf2f(unsigned short h) {
  unsigned u = (unsigned)h << 16;
  return __builtin_bit_cast(float, u);
}

// ---------------------------------------------------------------------------
// k0: split weights into bf16 hi/lo, concatenated rows [phi(32); g(32); theta(32)]
// ---------------------------------------------------------------------------
__global__ __launch_bounds__(256) void k0_prep(
    const float* __restrict__ wphi, const float* __restrict__ wtheta,
    const float* __restrict__ wg, unsigned short* __restrict__ Whi,
    unsigned short* __restrict__ Wlo)
{
  const int idx = blockIdx.x * 256 + threadIdx.x;
  if (idx >= 96 * 64) return;
  const int u = idx >> 6, c = idx & 63;
  const float w = (u < 32) ? wphi[u * 64 + c]
                : (u < 64) ? wg[(u - 32) * 64 + c]
                           : wtheta[(u - 64) * 64 + c];
  const unsigned short h = f2bf(w);
  Whi[idx] = h;
  Wlo[idx] = f2bf(w - bf2f(h));
}

// ---------------------------------------------------------------------------
// k1: MFMA conv (split bf16) + exp + att (MFMA over LDS E arrays) + T store.
// Grid (512, 8): blockIdx.x = 64-view-col tile, blockIdx.y = batch.
// 384 threads = 6 waves; wave w owns conv channels [16w, 16w+16):
//   w 0,1 = phi; w 2,3 = g; w 4,5 = theta.
// ---------------------------------------------------------------------------
__global__ __launch_bounds__(384) void k1_conv(
    const float* __restrict__ x, const unsigned short* __restrict__ Whi,
    const unsigned short* __restrict__ Wlo, unsigned short* __restrict__ Tg,
    float* __restrict__ attG, float* __restrict__ sums)
{
  __shared__ float xs[64 * 128];           // x tile, XOR-swizzled [c][pos^..]
  __shared__ unsigned short E[4][64 * 64]; // EpH, EpL, EgH, EgL (XOR-swizzled rows)

  const int tid = threadIdx.x;
  const int b = blockIdx.y;
  const int n0 = blockIdx.x * 64;
  const int w = tid >> 6;            // wave 0..5
  const int l = tid & 63;
  const int lr = l & 15, g = l >> 4; // fragment row/col, k-group
  const float* xb = x + (size_t)b * 64 * HW;

  // stage x tile: 64 ch x 128 pos (pos q: h = q>>6, col = n0 + (q&63))
  for (int k = tid; k < 2048; k += 384) {
    const int c = k >> 5, q0 = (k & 31) * 4;
    const float4 v = *(const float4*)(xb + (size_t)c * HW + (q0 >> 6) * NPOS + n0 + (q0 & 63));
    *(float4*)&xs[c * 128 + (q0 ^ (((c >> 3) & 3) << 4))] = v;
  }

  // weight A-fragments for this wave's 16 output channels (bf16 hi/lo)
  const int u0 = w * 16;
  short8 wh[2], wl[2];
  #pragma unroll
  for (int ks = 0; ks < 2; ++ks) {
    const size_t off = (size_t)(u0 + lr) * 64 + ks * 32 + g * 8;
    wh[ks] = *(const short8*)(Whi + off);
    wl[ks] = *(const short8*)(Wlo + off);
  }
  __syncthreads();

  // conv: D[ch 16 x pos 16] tiles, 8 pos-tiles, K=64 in 2 ksteps, 3-product split
  f32x4 acc[8] = {{0.f,0.f,0.f,0.f},{0.f,0.f,0.f,0.f},{0.f,0.f,0.f,0.f},{0.f,0.f,0.f,0.f},
                  {0.f,0.f,0.f,0.f},{0.f,0.f,0.f,0.f},{0.f,0.f,0.f,0.f},{0.f,0.f,0.f,0.f}};
  #pragma unroll
  for (int ks = 0; ks < 2; ++ks) {
    #pragma unroll
    for (int pt = 0; pt < 8; ++pt) {
      short8 xh, xl;
      const int base = (ks * 32 + g * 8) * 128 + ((pt * 16 + lr) ^ (g << 4));
      #pragma unroll
      for (int e = 0; e < 8; ++e) {
        const float f = xs[base + e * 128];
        const unsigned short h = f2bf(f);
        xh[e] = (short)h;
        xl[e] = (short)f2bf(f - bf2f(h));
      }
      acc[pt] = __builtin_amdgcn_mfma_f32_16x16x32_bf16(wh[ks], xh, acc[pt], 0, 0, 0);
      acc[pt] = __builtin_amdgcn_mfma_f32_16x16x32_bf16(wh[ks], xl, acc[pt], 0, 0, 0);
      acc[pt] = __builtin_amdgcn_mfma_f32_16x16x32_bf16(wl[ks], xh, acc[pt], 0, 0, 0);
    }
  }

  float ssum = 0.f;
  if (w < 4) {
    // exp + write E (view rows c' = 2i+h, cols n local, XOR-swizzled)
    const int iBase = (w & 1) * 16;
    unsigned short* Eh = (w < 2) ? E[0] : E[2];
    unsigned short* El = (w < 2) ? E[1] : E[3];
    #pragma unroll
    for (int pt = 0; pt < 8; ++pt) {
      const int h = pt >> 2, nc = (pt & 3) * 16 + lr;
      #pragma unroll
      for (int r = 0; r < 4; ++r) {
        const float e = __expf(acc[pt][r]);
        ssum += e;
        const int cp = 2 * (iBase + g * 4 + r) + h;
        const unsigned short eh = f2bf(e);
        const int el = cp * 64 + (nc ^ ((cp & 7) << 3));
        Eh[el] = eh;
        El[el] = f2bf(e - bf2f(eh));
      }
    }
  }
  __syncthreads();

  if (w < 4) {
    // att[c'][d'] += sum_n Eg[c'][n]*Ep[d'][n], MFMA split bf16; wave owns c'-tile w
    const int c0 = w * 16;
    f32x4 aacc[4] = {{0.f,0.f,0.f,0.f},{0.f,0.f,0.f,0.f},{0.f,0.f,0.f,0.f},{0.f,0.f,0.f,0.f}};
    #pragma unroll
    for (int ks = 0; ks < 2; ++ks) {
      const int kb = ks * 32 + g * 8;
      const int arow = c0 + lr;
      const int ael = arow * 64 + (kb ^ ((arow & 7) << 3));
      const short8 agh = *(const short8*)&E[2][ael];
      const short8 agl = *(const short8*)&E[3][ael];
      #pragma unroll
      for (int nt = 0; nt < 4; ++nt) {
        const int brow = nt * 16 + lr;
        const int bel = brow * 64 + (kb ^ ((brow & 7) << 3));
        const short8 bph = *(const short8*)&E[0][bel];
        const short8 bpl = *(const short8*)&E[1][bel];
        aacc[nt] = __builtin_amdgcn_mfma_f32_16x16x32_bf16(agh, bph, aacc[nt], 0, 0, 0);
        aacc[nt] = __builtin_amdgcn_mfma_f32_16x16x32_bf16(agh, bpl, aacc[nt], 0, 0, 0);
        aacc[nt] = __builtin_amdgcn_mfma_f32_16x16x32_bf16(agl, bph, aacc[nt], 0, 0, 0);
      }
    }
    float* attB = attG + b * 4096;
    #pragma unroll
    for (int nt = 0; nt < 4; ++nt)
      #pragma unroll
      for (int r = 0; r < 4; ++r)
        atomicAdd(&attB[(c0 + g * 4 + r) * 64 + nt * 16 + lr], aacc[nt][r]);
    // softmax denominators: w<2 -> Sp (sums[b]), w 2,3 -> Sg (sums[8+b])
    #pragma unroll
    for (int off = 32; off > 0; off >>= 1) ssum += __shfl_down(ssum, off);
    if (l == 0) atomicAdd(&sums[(w < 2 ? 0 : 8) + b], ssum);
  } else {
    // theta -> T global, view layout [c'=2i+h][n]
    unsigned short* Tb = Tg + (size_t)b * 64 * NPOS;
    const int iB = (w - 4) * 16;
    #pragma unroll
    for (int pt = 0; pt < 8; ++pt) {
      const int h = pt >> 2;
      const int col = n0 + (pt & 3) * 16 + lr;
      #pragma unroll
      for (int r = 0; r < 4; ++r) {
        const int cp = 2 * (iB + g * 4 + r) + h;
        Tb[(size_t)cp * NPOS + col] = f2bf(acc[pt][r]);
      }
    }
  }
}

// ---------------------------------------------------------------------------
// k3: M[b][h][o][d] = (1/(Sp*Sg)) * sum_i wm[o][i] * att[b][2i+h][d]  (bf16)
// ---------------------------------------------------------------------------
__global__ __launch_bounds__(256) void k3_mmat(
    const float* __restrict__ attG, const float* __restrict__ sums,
    const float* __restrict__ wm, unsigned short* __restrict__ M)
{
  __shared__ float att_s[64][64];
  __shared__ float wms[64][32];
  const int tid = threadIdx.x;
  const int b = blockIdx.x >> 1, h = blockIdx.x & 1;
  const float* attB = attG + b * 4096;
  for (int k = tid; k < 4096; k += 256) att_s[k >> 6][k & 63] = attB[k];
  for (int k = tid; k < 2048; k += 256) wms[k >> 5][k & 31] = wm[k];
  __syncthreads();
  const float scale = 1.f / (sums[b] * sums[8 + b]);
  for (int idx = tid; idx < 4096; idx += 256) {
    const int o = idx >> 6, d = idx & 63;
    float a = 0.f;
    #pragma unroll
    for (int i = 0; i < 32; ++i)
      a = __builtin_fmaf(wms[o][i], att_s[2 * i + h][d], a);
    M[(size_t)((b * 2 + h) * 64 + o) * 64 + d] = f2bf(a * scale);
  }
}

// ---------------------------------------------------------------------------
// k4: out[b][o][h*32768+n] = sum_d M[b][h][o][d] * Tv[d][n]   (MFMA bf16)
// ---------------------------------------------------------------------------
__global__ __launch_bounds__(256) void k4_out(
    const unsigned short* __restrict__ Tg, const unsigned short* __restrict__ M,
    float* __restrict__ out)
{
  __shared__ unsigned short Mlds[2][64][88];
  __shared__ unsigned short Tlds[64][88];
  const int tid = threadIdx.x;
  const int b = blockIdx.y, cb = blockIdx.x;
  const unsigned short* Tb = Tg + (size_t)b * 64 * NPOS;
  const unsigned short* Mb = M + (size_t)b * 2 * 4096;

  for (int k = tid; k < 2048; k += 256) {
    const int h = k >> 10, o = (k >> 4) & 63, q = k & 15;
    const ushort4 v = *(const ushort4*)(Mb + (size_t)(h * 64 + o) * 64 + q * 4);
    *(ushort4*)&Mlds[h][o][q * 4] = v;
  }
  const int wave = tid >> 6, lane = tid & 63;
  const int lr = lane & 15;
  const int lkb = (lane >> 4) * 8;
  float* outb = out + (size_t)b * 64 * HW;

  for (int t = 0; t < 8; ++t) {
    const int n0 = (cb * 8 + t) * 64;
    __syncthreads();
    for (int k = tid; k < 1024; k += 256) {
      const int d = k >> 4, q = k & 15;
      const ushort4 v = *(const ushort4*)(Tb + (size_t)d * NPOS + n0 + q * 4);
      Tlds[q * 4 + 0][d] = v.x; Tlds[q * 4 + 1][d] = v.y;
      Tlds[q * 4 + 2][d] = v.z; Tlds[q * 4 + 3][d] = v.w;
    }
    __syncthreads();
    #pragma unroll
    for (int h = 0; h < 2; ++h) {
      #pragma unroll
      for (int nb = 0; nb < 4; ++nb) {
        f32x4 acc = {0.f, 0.f, 0.f, 0.f};
        #pragma unroll
        for (int ks = 0; ks < 2; ++ks) {
          const short8 av = *(const short8*)&Mlds[h][wave * 16 + lr][ks * 32 + lkb];
          const short8 bv = *(const short8*)&Tlds[nb * 16 + lr][ks * 32 + lkb];
          acc = __builtin_amdgcn_mfma_f32_16x16x32_bf16(av, bv, acc, 0, 0, 0);
        }
        float* o0 = outb + (size_t)(wave * 16 + (lane >> 4) * 4) * HW
                  + (size_t)h * NPOS + n0 + nb * 16 + lr;
        #pragma unroll
        for (int r = 0; r < 4; ++r) o0[(size_t)r * HW] = acc[r];
      }
    }
  }
}

// ---------------------------------------------------------------------------
extern "C" void kernel_launch(void* const* d_in, const int* in_sizes, int n_in,
                              void* d_out, int out_size, void* d_ws, size_t ws_size,
                              hipStream_t stream)
{
  const float* x      = (const float*)d_in[0];
  const float* wphi   = (const float*)d_in[1];
  const float* wtheta = (const float*)d_in[2];
  const float* wg     = (const float*)d_in[3];
  const float* wm     = (const float*)d_in[4];
  float* out = (float*)d_out;

  char* ws = (char*)d_ws;
  unsigned short* Tg  = (unsigned short*)ws;                        // 33,554,432 B
  unsigned short* Whi = (unsigned short*)(ws + 33554432);           //     12,288 B
  unsigned short* Wlo = (unsigned short*)(ws + 33566720);           //     12,288 B
  float* attG         = (float*)(ws + 33579008);                    //    131,072 B
  float* sums         = (float*)(ws + 33710080);                    //         64 B
  unsigned short* M   = (unsigned short*)(ws + 33710144);           //    131,072 B

  hipMemsetAsync(attG, 0, 131072 + 64, stream);
  k0_prep<<<dim3(24), 256, 0, stream>>>(wphi, wtheta, wg, Whi, Wlo);
  k1_conv<<<dim3(512, 8), 384, 0, stream>>>(x, Whi, Wlo, Tg, attG, sums);
  k3_mmat<<<dim3(16), 256, 0, stream>>>(attG, sums, wm, M);
  k4_out<<<dim3(64, 8), 256, 0, stream>>>(Tg, M, out);
}

// Round 3
// 289.056 us; speedup vs baseline: 1.5955x; 1.0616x over previous
//
#include <hip/hip_runtime.h>

typedef __attribute__((ext_vector_type(8))) short short8;
typedef __attribute__((ext_vector_type(4))) float f32x4;

#define HW 65536
#define NPOS 32768

__device__ __forceinline__ unsigned short f2bf(float f) {
  unsigned u = __builtin_bit_cast(unsigned, f);
  u += 0x7fffu + ((u >> 16) & 1u);
  return (unsigned short)(u >> 16);
}
__device__ __forceinline__ float bf2f(unsigned short h) {
  unsigned u = (unsigned)h << 16;
  return __builtin_bit_cast(float, u);
}
__device__ __forceinline__ int slot3(int r) { return (r ^ (r >> 3)) & 7; }
__device__ __forceinline__ int slot4(int r) { return (r ^ (r >> 2)) & 15; }

// ---------------------------------------------------------------------------
// k0: split conv weights to bf16 hi/lo; rows 0-31 = phi, 32-63 = g.
// ---------------------------------------------------------------------------
__global__ __launch_bounds__(256) void k0_prep(
    const float* __restrict__ wphi, const float* __restrict__ wg,
    unsigned short* __restrict__ Whi, unsigned short* __restrict__ Wlo)
{
  const int idx = blockIdx.x * 256 + threadIdx.x;  // 4096 total
  const int u = idx >> 6, c = idx & 63;
  const float w = (u < 32) ? wphi[u * 64 + c] : wg[(u - 32) * 64 + c];
  const unsigned short h = f2bf(w);
  Whi[idx] = h;
  Wlo[idx] = f2bf(w - bf2f(h));
}

// ---------------------------------------------------------------------------
// k1: phi/g conv (MFMA, split-bf16) + exp + att partials (MFMA) + sums.
// Grid (128, 8): 256 view-cols per block. 512 thr = 8 waves.
// Wave w: conv ch-tile ct=w&3 (0,1=phi; 2,3=g), pos-tiles (w>>2)*4..+3 (h=w>>2).
//         att tile-pair: cti=w>>1, dti=(w&1)*2+{0,1}; partials -> attP[b][blk].
// ---------------------------------------------------------------------------
__global__ __launch_bounds__(512, 4) void k1_att(
    const float* __restrict__ x, const unsigned short* __restrict__ Whi,
    const unsigned short* __restrict__ Wlo, float* __restrict__ attP,
    float* __restrict__ sums)
{
  __shared__ unsigned short xhs[128 * 64];   // [q][c] bf16-hi, slot3-swizzled
  __shared__ unsigned short xls[128 * 64];   // [q][c] bf16-lo
  __shared__ unsigned short E[4][64 * 64];   // EpH, EpL, EgH, EgL  [c'][n]

  const int tid = threadIdx.x;
  const int b = blockIdx.y, blk = blockIdx.x;
  const int n0 = blk * 256;
  const int w = tid >> 6, l = tid & 63;
  const int lr = l & 15, g = l >> 4;
  const int ct = w & 3, hw4 = w >> 2;
  const int cti = w >> 1;
  const float* xb = x + (size_t)b * 64 * HW;

  // conv A-fragments (weights)
  short8 wh[2], wl[2];
  #pragma unroll
  for (int ks = 0; ks < 2; ++ks) {
    const size_t off = (size_t)(ct * 16 + lr) * 64 + ks * 32 + g * 8;
    wh[ks] = *(const short8*)(Whi + off);
    wl[ks] = *(const short8*)(Wlo + off);
  }

  f32x4 aacc[2] = {{0.f, 0.f, 0.f, 0.f}, {0.f, 0.f, 0.f, 0.f}};
  float ssum = 0.f;

  // prologue: register-load sub-tile 0
  float4 xr[4];
  #pragma unroll
  for (int it = 0; it < 4; ++it) {
    const int c = (tid >> 4) + (it & 1) * 32;
    xr[it] = *(const float4*)(xb + (size_t)c * HW + (it >> 1) * NPOS + n0 + (tid & 15) * 4);
  }

  for (int t = 0; t < 4; ++t) {
    // convert + write x tile (transposed [q][c], hi/lo planes)
    #pragma unroll
    for (int it = 0; it < 4; ++it) {
      const int c = (tid >> 4) + (it & 1) * 32;
      #pragma unroll
      for (int j = 0; j < 4; ++j) {
        const float f = ((const float*)&xr[it])[j];
        const int q = (it >> 1) * 64 + (tid & 15) * 4 + j;
        const int idx = q * 64 + (c ^ (slot3(q) << 3));
        const unsigned short hi = f2bf(f);
        xhs[idx] = hi;
        xls[idx] = f2bf(f - bf2f(hi));
      }
    }
    __syncthreads();  // bar1: x tile ready; prev att done everywhere

    // prefetch next sub-tile into regs (overlaps conv/att below)
    if (t < 3) {
      const int n0s = n0 + (t + 1) * 64;
      #pragma unroll
      for (int it = 0; it < 4; ++it) {
        const int c = (tid >> 4) + (it & 1) * 32;
        xr[it] = *(const float4*)(xb + (size_t)c * HW + (it >> 1) * NPOS + n0s + (tid & 15) * 4);
      }
    }

    // conv: 4 pos-tiles, K=64, 3-product split
    f32x4 cacc[4] = {{0.f,0.f,0.f,0.f},{0.f,0.f,0.f,0.f},{0.f,0.f,0.f,0.f},{0.f,0.f,0.f,0.f}};
    #pragma unroll
    for (int pti = 0; pti < 4; ++pti) {
      const int q = (hw4 * 4 + pti) * 16 + lr;
      const int sw = slot3(q) << 3;
      #pragma unroll
      for (int ks = 0; ks < 2; ++ks) {
        const int bi = q * 64 + ((ks * 32 + g * 8) ^ sw);
        const short8 bxh = *(const short8*)&xhs[bi];
        const short8 bxl = *(const short8*)&xls[bi];
        cacc[pti] = __builtin_amdgcn_mfma_f32_16x16x32_bf16(wh[ks], bxh, cacc[pti], 0, 0, 0);
        cacc[pti] = __builtin_amdgcn_mfma_f32_16x16x32_bf16(wh[ks], bxl, cacc[pti], 0, 0, 0);
        cacc[pti] = __builtin_amdgcn_mfma_f32_16x16x32_bf16(wl[ks], bxh, cacc[pti], 0, 0, 0);
      }
    }

    // exp + E write (view rows c' = 2i + h, split bf16)
    {
      unsigned short* EH = (ct < 2) ? E[0] : E[2];
      unsigned short* EL = (ct < 2) ? E[1] : E[3];
      #pragma unroll
      for (int pti = 0; pti < 4; ++pti) {
        const int n = pti * 16 + lr;
        #pragma unroll
        for (int r = 0; r < 4; ++r) {
          const float e = __expf(cacc[pti][r]);
          ssum += e;
          const int cp = 2 * ((ct & 1) * 16 + g * 4 + r) + hw4;
          const int idx = cp * 64 + (n ^ (slot3(cp) << 3));
          const unsigned short eh = f2bf(e);
          EH[idx] = eh;
          EL[idx] = f2bf(e - bf2f(eh));
        }
      }
    }
    __syncthreads();  // bar2: E ready

    // att partial: att[c'][d'] += sum_n Eg[c'][n] * Ep[d'][n]
    #pragma unroll
    for (int ks = 0; ks < 2; ++ks) {
      const int ar = cti * 16 + lr;
      const int ai = ar * 64 + ((ks * 32 + g * 8) ^ (slot3(ar) << 3));
      const short8 agh = *(const short8*)&E[2][ai];
      const short8 agl = *(const short8*)&E[3][ai];
      #pragma unroll
      for (int j = 0; j < 2; ++j) {
        const int dr = ((w & 1) * 2 + j) * 16 + lr;
        const int bi = dr * 64 + ((ks * 32 + g * 8) ^ (slot3(dr) << 3));
        const short8 bph = *(const short8*)&E[0][bi];
        const short8 bpl = *(const short8*)&E[1][bi];
        aacc[j] = __builtin_amdgcn_mfma_f32_16x16x32_bf16(agh, bph, aacc[j], 0, 0, 0);
        aacc[j] = __builtin_amdgcn_mfma_f32_16x16x32_bf16(agh, bpl, aacc[j], 0, 0, 0);
        aacc[j] = __builtin_amdgcn_mfma_f32_16x16x32_bf16(agl, bph, aacc[j], 0, 0, 0);
      }
    }
  }

  // flush att partials (contention-free: per-block buffer)
  float* ap = attP + ((size_t)(b * 128 + blk)) * 4096;
  #pragma unroll
  for (int j = 0; j < 2; ++j)
    #pragma unroll
    for (int r = 0; r < 4; ++r)
      ap[(cti * 16 + g * 4 + r) * 64 + ((w & 1) * 2 + j) * 16 + lr] = aacc[j][r];

  // softmax denominators
  #pragma unroll
  for (int off = 32; off > 0; off >>= 1) ssum += __shfl_down(ssum, off);
  if (l == 0) atomicAdd(&sums[(ct < 2 ? 0 : 8) + b], ssum);
}

// ---------------------------------------------------------------------------
// k3: reduce att partials; N[b][oo=h*64+o][cc=e*64+c] =
//     scale * sum_j ( sum_i wm[o][i]*att[2i+h][2j+e] ) * Wth[j][c]  -> bf16 hi/lo
// Grid (8), 1024 threads.
// ---------------------------------------------------------------------------
__global__ __launch_bounds__(1024) void k3_nmat(
    const float* __restrict__ attP, const float* __restrict__ sums,
    const float* __restrict__ wm, const float* __restrict__ wtheta,
    unsigned short* __restrict__ Nhi, unsigned short* __restrict__ Nlo)
{
  __shared__ float att_s[4096];
  __shared__ float Mp[2][64][64];
  __shared__ float wms[64][32];
  __shared__ float wts[32][64];
  const int tid = threadIdx.x;
  const int b = blockIdx.x;

  if (tid < 512) {
    if (tid < 256) { for (int k = tid; k < 2048; k += 256) wms[k >> 5][k & 31] = wm[k]; }
    else           { for (int k = tid - 256; k < 2048; k += 256) wts[k >> 6][k & 63] = wtheta[k]; }
  }
  for (int e = tid; e < 4096; e += 1024) {
    const float* p = attP + (size_t)b * 128 * 4096 + e;
    float s0 = 0.f, s1 = 0.f, s2 = 0.f, s3 = 0.f;
    for (int q = 0; q < 128; q += 4) {
      s0 += p[(size_t)q * 4096];
      s1 += p[(size_t)(q + 1) * 4096];
      s2 += p[(size_t)(q + 2) * 4096];
      s3 += p[(size_t)(q + 3) * 4096];
    }
    att_s[e] = (s0 + s1) + (s2 + s3);
  }
  __syncthreads();
  for (int idx = tid; idx < 8192; idx += 1024) {
    const int h = idx >> 12, o = (idx >> 6) & 63, d = idx & 63;
    float s = 0.f;
    #pragma unroll
    for (int i = 0; i < 32; ++i)
      s = __builtin_fmaf(wms[o][i], att_s[(2 * i + h) * 64 + d], s);
    Mp[h][o][d] = s;
  }
  __syncthreads();
  const float scale = 1.f / (sums[b] * sums[8 + b]);
  for (int idx = tid; idx < 16384; idx += 1024) {
    const int oo = idx >> 7, cc = idx & 127;
    const int h = oo >> 6, o = oo & 63, e = cc >> 6, c = cc & 63;
    float s = 0.f;
    #pragma unroll
    for (int j = 0; j < 32; ++j)
      s = __builtin_fmaf(Mp[h][o][2 * j + e], wts[j][c], s);
    s *= scale;
    const unsigned short hi = f2bf(s);
    Nhi[(size_t)b * 16384 + idx] = hi;
    Nlo[(size_t)b * 16384 + idx] = f2bf(s - bf2f(hi));
  }
}

// ---------------------------------------------------------------------------
// k5: out[b][o][h*NPOS+n] = sum_cc N[b][h*64+o][cc] * x[b][cc&63][(cc>>6)*NPOS+n]
// Grid (512, 8): 64 cols per block. 512 thr = 8 waves; wave w owns oo-rows
// [16w,16w+16). MFMA split-bf16, K=128.
// ---------------------------------------------------------------------------
__global__ __launch_bounds__(512, 4) void k5_out(
    const float* __restrict__ x, const unsigned short* __restrict__ Nhi,
    const unsigned short* __restrict__ Nlo, float* __restrict__ out)
{
  __shared__ unsigned short Xh[64 * 128];   // [n][cc] bf16-hi, slot4-swizzled
  __shared__ unsigned short Xl[64 * 128];
  const int tid = threadIdx.x;
  const int b = blockIdx.y, n0 = blockIdx.x * 64;
  const int w = tid >> 6, l = tid & 63;
  const int lr = l & 15, g = l >> 4;
  const float* xb = x + (size_t)b * 64 * HW;

  // A-fragments: N rows 16w..16w+15, K=128 (4 ksteps), hi/lo
  short8 ah[4], al[4];
  #pragma unroll
  for (int ks = 0; ks < 4; ++ks) {
    const size_t off = (size_t)b * 16384 + (size_t)(w * 16 + lr) * 128 + ks * 32 + g * 8;
    ah[ks] = *(const short8*)(Nhi + off);
    al[ks] = *(const short8*)(Nlo + off);
  }

  // stage X2 tile transposed: [n][cc], hi/lo
  #pragma unroll
  for (int it = 0; it < 4; ++it) {
    const int cc = (tid >> 4) + it * 32;
    const int c = cc & 63, e = cc >> 6;
    const float4 v = *(const float4*)(xb + (size_t)c * HW + e * NPOS + n0 + (tid & 15) * 4);
    #pragma unroll
    for (int j = 0; j < 4; ++j) {
      const float f = ((const float*)&v)[j];
      const int n = (tid & 15) * 4 + j;
      const int idx = n * 128 + (cc ^ (slot4(n) << 3));
      const unsigned short hi = f2bf(f);
      Xh[idx] = hi;
      Xl[idx] = f2bf(f - bf2f(hi));
    }
  }
  __syncthreads();

  const int hh = w >> 2;                    // output half (oo>>6)
  const int obase = (w & 3) * 16 + g * 4;   // o = obase + r
  float* ob = out + (size_t)b * 64 * HW + (size_t)hh * NPOS;

  #pragma unroll
  for (int ct4 = 0; ct4 < 4; ++ct4) {
    f32x4 acc = {0.f, 0.f, 0.f, 0.f};
    const int row = ct4 * 16 + lr;
    const int sw = slot4(row) << 3;
    #pragma unroll
    for (int ks = 0; ks < 4; ++ks) {
      const int bi = row * 128 + ((ks * 32 + g * 8) ^ sw);
      const short8 bh = *(const short8*)&Xh[bi];
      const short8 bl = *(const short8*)&Xl[bi];
      acc = __builtin_amdgcn_mfma_f32_16x16x32_bf16(ah[ks], bh, acc, 0, 0, 0);
      acc = __builtin_amdgcn_mfma_f32_16x16x32_bf16(ah[ks], bl, acc, 0, 0, 0);
      acc = __builtin_amdgcn_mfma_f32_16x16x32_bf16(al[ks], bh, acc, 0, 0, 0);
    }
    const int n = n0 + ct4 * 16 + lr;
    #pragma unroll
    for (int r = 0; r < 4; ++r)
      ob[(size_t)(obase + r) * HW + n] = acc[r];
  }
}

// ---------------------------------------------------------------------------
extern "C" void kernel_launch(void* const* d_in, const int* in_sizes, int n_in,
                              void* d_out, int out_size, void* d_ws, size_t ws_size,
                              hipStream_t stream)
{
  const float* x      = (const float*)d_in[0];
  const float* wphi   = (const float*)d_in[1];
  const float* wtheta = (const float*)d_in[2];
  const float* wg     = (const float*)d_in[3];
  const float* wm     = (const float*)d_in[4];
  float* out = (float*)d_out;

  char* ws = (char*)d_ws;
  float* attP         = (float*)ws;                                 // 16,777,216 B
  unsigned short* Whi = (unsigned short*)(ws + 16777216);           //      8,192 B
  unsigned short* Wlo = (unsigned short*)(ws + 16785408);           //      8,192 B
  unsigned short* Nhi = (unsigned short*)(ws + 16793600);           //    262,144 B
  unsigned short* Nlo = (unsigned short*)(ws + 17055744);           //    262,144 B
  float* sums         = (float*)(ws + 17317888);                    //         64 B

  hipMemsetAsync(sums, 0, 64, stream);
  k0_prep<<<dim3(16), 256, 0, stream>>>(wphi, wg, Whi, Wlo);
  k1_att<<<dim3(128, 8), 512, 0, stream>>>(x, Whi, Wlo, attP, sums);
  k3_nmat<<<dim3(8), 1024, 0, stream>>>(attP, sums, wm, wtheta, Nhi, Nlo);
  k5_out<<<dim3(512, 8), 512, 0, stream>>>(x, Nhi, Nlo, out);
}